// Round 6
// baseline (29.713 us; speedup 1.0000x reference)
//
#include <hip/hip_runtime.h>
#include <math.h>

#define NPRED 22743
#define NB 16
#define NT 20
#define RBLK 89            // noobj blocks per image (1 row/thread, 256 rows/block)
#define TBLK 5             // target blocks per image (4 waves x 1 target)
#define XTOT (RBLK + TBLK) // 94 blocks per image

__device__ __constant__ float c_anch[9][2] = {
    {10.f,13.f},{16.f,30.f},{33.f,23.f},{30.f,61.f},{62.f,45.f},
    {59.f,119.f},{116.f,90.f},{156.f,198.f},{373.f,326.f}};

__device__ __forceinline__ float sigm(float x){ return 1.0f/(1.0f+expf(-x)); }

__device__ __forceinline__ const float* row_base(const float* f0, const float* f1,
                                                 const float* f2, int b, int j){
    if (j < 17328) return f0 + ((size_t)b*17328 + j)*85;
    if (j < 21660) return f1 + ((size_t)b*4332  + (j-17328))*85;
    return f2 + ((size_t)b*1083 + (j-21660))*85;
}

// constant-divisor geometry per level
__device__ __forceinline__ void row_geom(int j, float& scale, int& cx, int& cy, int& aidx){
    int local, fi;
    if (j < 17328){      local = j;        scale = 8.f;  cx = local/228; cy = (local/3)%76; fi = 0; }
    else if (j < 21660){ local = j-17328;  scale = 16.f; cx = local/114; cy = (local/3)%38; fi = 1; }
    else {               local = j-21660;  scale = 32.f; cx = local/57;  cy = (local/3)%19; fi = 2; }
    aidx = fi*3 + local%3;
}

__device__ __forceinline__ int best_anchor(float tw, float th){
    const float at = tw*th;
    int best = 0; float bi = -1.f;
    #pragma unroll
    for (int a = 0; a < 9; ++a){
        float aw = c_anch[a][0], ah = c_anch[a][1];
        float inter = fminf(tw,aw)*fminf(th,ah);
        float iou = inter/(at + aw*ah - inter);
        if (iou > bi){ bi = iou; best = a; }
    }
    return best;
}

// positive index only (no logf)
__device__ __forceinline__ int pos_index(float cx, float cy, float tw, float th){
    const int best = best_anchor(tw,th);
    const int fi = best/3, bidx = best%3;
    const float scale = (fi==0)?8.f:((fi==1)?16.f:32.f);
    const int   hh    = (fi==0)?76 :((fi==1)?38 :19);
    const int   start = (fi==0)?0  :((fi==1)?17328:21660);
    float sx = cx/scale, sy = cy/scale;
    float fx = sx - floorf(sx); if (fx == 0.f) fx = 1.f;
    float fy = sy - floorf(sy); if (fy == 0.f) fy = 1.f;
    const int tlx = (int)(sx - fx);
    const int tly = (int)(sy - fy);
    return start + (tlx*hh + tly)*3 + bidx;
}

// full decode (with logf) — for the target-loss path
__device__ __forceinline__ void target_decode(float cx, float cy, float tw, float th,
                                              int& pidx, float& fx, float& fy,
                                              float& gtw, float& gth){
    const int best = best_anchor(tw,th);
    const int fi = best/3, bidx = best%3;
    const float scale = (fi==0)?8.f:((fi==1)?16.f:32.f);
    const int   hh    = (fi==0)?76 :((fi==1)?38 :19);
    const int   start = (fi==0)?0  :((fi==1)?17328:21660);
    const float aw = c_anch[best][0], ah = c_anch[best][1];
    float sx = cx/scale, sy = cy/scale;
    fx = sx - floorf(sx); if (fx == 0.f) fx = 1.f;
    fy = sy - floorf(sy); if (fy == 0.f) fy = 1.f;
    const int tlx = (int)(sx - fx);
    const int tly = (int)(sy - fy);
    gtw = logf(tw/aw); gth = logf(th/ah);
    pidx = start + (tlx*hh + tly)*3 + bidx;
}

// IoU-threshold test + softplus for one prediction row; div-free:
// max_t iou < 0.5  <=>  forall t: 3*inter_t < a1 + a2_t
__device__ __forceinline__ bool row_test(int j, float4 r4, float p4,
                                         const float4* srect, const float* sa2,
                                         float& sp){
    float scale; int cx, cy, aidx;
    row_geom(j, scale, cx, cy, aidx);
    const float aw = c_anch[aidx][0], ah = c_anch[aidx][1];
    const float pcx = ((float)cx + sigm(r4.x))*scale;
    const float pcy = ((float)cy + sigm(r4.y))*scale;
    const float pw = aw*expf(r4.z);
    const float ph = ah*expf(r4.w);
    const float a1 = pw*ph;
    const float pxl = pcx - pw*0.5f, pyl = pcy - ph*0.5f;
    const float pxr = pcx + pw*0.5f, pyr = pcy + ph*0.5f;
    float md = -1.f;
    #pragma unroll
    for (int t = 0; t < NT; ++t){
        float4 T = srect[t];   // lx, ly, rx, ry
        float iw = fmaxf(fminf(pxr, T.z) - fmaxf(pxl, T.x), 0.f);
        float ih = fmaxf(fminf(pyr, T.w) - fmaxf(pyl, T.y), 0.f);
        float inter = iw*ih;
        md = fmaxf(md, fmaf(3.f, inter, -(a1 + sa2[t])));
    }
    // -max(log1p(-sigmoid(x)),-100) == min(softplus(x),100)
    sp = fminf(log1pf(expf(p4)), 100.f);
    return md < 0.f;
}

// ---------------- Main kernel ----------------
__global__ __launch_bounds__(256) void yolo_main(
        const float* __restrict__ f0, const float* __restrict__ f1,
        const float* __restrict__ f2,
        const float* __restrict__ tb, const int* __restrict__ tlab,
        const float* __restrict__ tsc,
        float* __restrict__ part_s, int* __restrict__ part_c,
        float* __restrict__ pbox, float* __restrict__ pobj,
        float* __restrict__ pcls,
        float* __restrict__ corr_s, int* __restrict__ corr_c){
    const int b   = blockIdx.y;
    const int x   = blockIdx.x;
    const int tid = threadIdx.x;

    __shared__ float4 sbox[NT];    // raw cxywh
    __shared__ float4 srect[NT];   // lx, ly, rx, ry
    __shared__ float  sa2[NT];     // target areas
    if (tid < NT){
        float4 T = ((const float4*)tb)[b*NT + tid];
        sbox[tid]  = T;
        srect[tid] = make_float4(T.x - T.z*0.5f, T.y - T.w*0.5f,
                                 T.x + T.z*0.5f, T.y + T.w*0.5f);
        sa2[tid] = T.z * T.w;
    }
    __syncthreads();

    if (x < RBLK){
        // ---- noobj path: 1 row per thread, no positive check (corrected later) ----
        const int j = x*256 + tid;
        const bool valid = (j < NPRED);
        const float* P = row_base(f0,f1,f2,b, valid ? j : 0);
        const float4 r4 = *reinterpret_cast<const float4*>(P);  // p0..p3 (dword-aligned ok)
        const float  p4 = P[4];

        float nb = 0.f; int cnt = 0;
        if (valid){
            float sp;
            bool qual = row_test(j, r4, p4, srect, sa2, sp);
            if (qual){ nb = sp; cnt = 1; }
        }
        #pragma unroll
        for (int off = 32; off > 0; off >>= 1){
            nb  += __shfl_down(nb, off);
            cnt += __shfl_down(cnt, off);
        }
        __shared__ float ws_s[4];
        __shared__ int   ws_c[4];
        const int wid = tid >> 6;
        if ((tid & 63) == 0){ ws_s[wid] = nb; ws_c[wid] = cnt; }
        __syncthreads();
        if (tid == 0){
            part_s[b*RBLK + x] = ws_s[0]+ws_s[1]+ws_s[2]+ws_s[3];
            part_c[b*RBLK + x] = ws_c[0]+ws_c[1]+ws_c[2]+ws_c[3];
        }
    } else {
        // ---- target path: one wave per target ----
        const int w    = tid >> 6;
        const int lane = tid & 63;
        const int t    = (x - RBLK)*4 + w;       // 0..19

        // per-lane positive index for dedup (lanes >= NT clamp to 19)
        const int bl = (lane < NT) ? lane : (NT-1);
        float4 BL = sbox[bl];
        int pidx_l = pos_index(BL.x, BL.y, BL.z, BL.w);
        // this wave's target
        float4 box = sbox[t];
        int pidx; float fx, fy, gtw, gth;
        target_decode(box.x, box.y, box.z, box.w, pidx, fx, fy, gtw, gth);
        unsigned long long mask = __ballot(pidx_l == pidx);
        const bool dup = (mask & ((1ull << t) - 1ull)) != 0ull;

        const float* p = row_base(f0,f1,f2,b,pidx);
        // broadcast row head (same address across lanes)
        const float4 r4 = *reinterpret_cast<const float4*>(p);
        const float  p4 = p[4];
        // correction test — bit-identical predicate to the noobj path
        float sp;
        bool qual = row_test(pidx, r4, p4, srect, sa2, sp);

        // class BCE spread across lanes
        const int lab = tlab[b*NT + t];
        float s;
        {
            float pc = sigm(p[5+lane]);
            float lg  = fmaxf(logf(pc),    -100.f);
            float lg1 = fmaxf(log1pf(-pc), -100.f);
            float tt = (lane == lab) ? 1.f : 0.f;
            s = -(tt*lg + (1.f-tt)*lg1);
        }
        if (lane < 16){
            int c = 64 + lane;
            float pc = sigm(p[5+c]);
            float lg  = fmaxf(logf(pc),    -100.f);
            float lg1 = fmaxf(log1pf(-pc), -100.f);
            float tt = (c == lab) ? 1.f : 0.f;
            s += -(tt*lg + (1.f-tt)*lg1);
        }
        #pragma unroll
        for (int off = 32; off > 0; off >>= 1) s += __shfl_down(s, off);

        if (lane == 0){
            const float w2 = 2.f - gtw*gth;
            float d0 = sigm(r4.x) - fx;
            float d1 = sigm(r4.y) - fy;
            float d2 = r4.z - gtw;
            float d3 = r4.w - gth;
            pbox[b*NT + t] = w2*(d0*d0 + d1*d1 + d2*d2 + d3*d3);
            float po = sigm(p4);
            float ts = tsc[b*NT + t];
            float lg  = fmaxf(logf(po),    -100.f);
            float lg1 = fmaxf(log1pf(-po), -100.f);
            pobj[b*NT + t] = -(ts*lg + (1.f-ts)*lg1);
            pcls[b*NT + t] = s;
            const bool take = qual && !dup;
            corr_s[b*NT + t] = take ? sp : 0.f;
            corr_c[b*NT + t] = take ? 1 : 0;
        }
    }
}

// ---------------- Finalize ----------------
__global__ __launch_bounds__(256) void yolo_final(
        const float* __restrict__ part_s, const int* __restrict__ part_c,
        const float* __restrict__ pbox, const float* __restrict__ pobj,
        const float* __restrict__ pcls,
        const float* __restrict__ corr_s, const int* __restrict__ corr_c,
        float* __restrict__ out){
    const int tid  = threadIdx.x;
    const int w    = tid >> 6;
    const int lane = tid & 63;
    __shared__ float rb[NB], ro[NB], rc[NB], rn[NB];
    for (int b = w; b < NB; b += 4){
        float s = 0.f; int c = 0;
        if (lane < RBLK){ s = part_s[b*RBLK + lane]; c = part_c[b*RBLK + lane]; }
        if (lane + 64 < RBLK){ s += part_s[b*RBLK + lane + 64]; c += part_c[b*RBLK + lane + 64]; }
        float A = 0.f, O = 0.f, C = 0.f, CS = 0.f; int CC = 0;
        if (lane < NT){
            A = pbox[b*NT + lane]; O = pobj[b*NT + lane]; C = pcls[b*NT + lane];
            CS = corr_s[b*NT + lane]; CC = corr_c[b*NT + lane];
        }
        #pragma unroll
        for (int off = 32; off > 0; off >>= 1){
            s  += __shfl_down(s, off);
            c  += __shfl_down(c, off);
            A  += __shfl_down(A, off);
            O  += __shfl_down(O, off);
            C  += __shfl_down(C, off);
            CS += __shfl_down(CS, off);
            CC += __shfl_down(CC, off);
        }
        if (lane == 0){
            float lb = A/(float)(NT*4);
            if (isinf(lb)) lb = 0.f;
            rb[b] = lb;
            ro[b] = O/(float)NT;
            rc[b] = C/(float)(NT*80);
            int   cnt = c - CC;
            float sum = s - CS;
            rn[b] = sum/(float)(cnt > 1 ? cnt : 1);
        }
    }
    __syncthreads();
    if (tid == 0){
        float sb=0.f, so=0.f, sc=0.f, sn=0.f;
        for (int b = 0; b < NB; ++b){ sb += rb[b]; so += ro[b]; sc += rc[b]; sn += rn[b]; }
        out[0] = sb/(float)NB;          // L_COORD * lbox.mean()
        out[1] = sc/(float)NB;          // L_CLS   * lcls.mean()
        out[2] = so/(float)NB;          // L_OBJ   * lobj.mean()
        out[3] = 0.5f*sn/(float)NB;     // L_NOOBJ * lnoobj.mean()
    }
}

extern "C" void kernel_launch(void* const* d_in, const int* in_sizes, int n_in,
                              void* d_out, int out_size, void* d_ws, size_t ws_size,
                              hipStream_t stream) {
    const float* f0  = (const float*)d_in[0];
    const float* f1  = (const float*)d_in[1];
    const float* f2  = (const float*)d_in[2];
    const float* tb  = (const float*)d_in[3];
    const int*   tlab= (const int*)  d_in[4];
    const float* tsc = (const float*)d_in[5];
    float* out = (float*)d_out;

    // ws layout — every slot plain-stored every call; no init, no atomics
    char* ws = (char*)d_ws;
    float* part_s = (float*)ws;                  // 16*89 f = 5696 B
    int*   part_c = (int*)  (ws + 5696);         // 16*89 i = 5696 B
    float* pbox   = (float*)(ws + 11392);        // 320 f
    float* pobj   = (float*)(ws + 12672);        // 320 f
    float* pcls   = (float*)(ws + 13952);        // 320 f
    float* corr_s = (float*)(ws + 15232);        // 320 f
    int*   corr_c = (int*)  (ws + 16512);        // 320 i

    dim3 grid(XTOT, NB);
    yolo_main<<<grid, 256, 0, stream>>>(f0, f1, f2, tb, tlab, tsc,
                                        part_s, part_c, pbox, pobj, pcls,
                                        corr_s, corr_c);
    yolo_final<<<1, 256, 0, stream>>>(part_s, part_c, pbox, pobj, pcls,
                                      corr_s, corr_c, out);
}

// Round 8
// 25.115 us; speedup vs baseline: 1.1831x; 1.1831x over previous
//
#include <hip/hip_runtime.h>
#include <math.h>

#define NPRED 22743
#define NB 16
#define NT 20
#define RBLK 45            // noobj blocks per image (2 rows/thread, 512 rows/block)
#define TBLK 5             // target blocks per image (4 waves x 1 target)
#define XTOT (RBLK + TBLK) // 50 blocks per image

typedef float nfloat4 __attribute__((ext_vector_type(4)));   // native vec for nontemporal builtin

__device__ __constant__ float c_anch[9][2] = {
    {10.f,13.f},{16.f,30.f},{33.f,23.f},{30.f,61.f},{62.f,45.f},
    {59.f,119.f},{116.f,90.f},{156.f,198.f},{373.f,326.f}};

__device__ __forceinline__ float sigm(float x){ return 1.0f/(1.0f+expf(-x)); }

__device__ __forceinline__ const float* row_base(const float* f0, const float* f1,
                                                 const float* f2, int b, int j){
    if (j < 17328) return f0 + ((size_t)b*17328 + j)*85;
    if (j < 21660) return f1 + ((size_t)b*4332  + (j-17328))*85;
    return f2 + ((size_t)b*1083 + (j-21660))*85;
}

// constant-divisor geometry per level
__device__ __forceinline__ void row_geom(int j, float& scale, int& cx, int& cy, int& aidx){
    int local, fi;
    if (j < 17328){      local = j;        scale = 8.f;  cx = local/228; cy = (local/3)%76; fi = 0; }
    else if (j < 21660){ local = j-17328;  scale = 16.f; cx = local/114; cy = (local/3)%38; fi = 1; }
    else {               local = j-21660;  scale = 32.f; cx = local/57;  cy = (local/3)%19; fi = 2; }
    aidx = fi*3 + local%3;
}

__device__ __forceinline__ int best_anchor(float tw, float th){
    const float at = tw*th;
    int best = 0; float bi = -1.f;
    #pragma unroll
    for (int a = 0; a < 9; ++a){
        float aw = c_anch[a][0], ah = c_anch[a][1];
        float inter = fminf(tw,aw)*fminf(th,ah);
        float iou = inter/(at + aw*ah - inter);
        if (iou > bi){ bi = iou; best = a; }
    }
    return best;
}

// positive index only (no logf)
__device__ __forceinline__ int pos_index(float cx, float cy, float tw, float th){
    const int best = best_anchor(tw,th);
    const int fi = best/3, bidx = best%3;
    const float scale = (fi==0)?8.f:((fi==1)?16.f:32.f);
    const int   hh    = (fi==0)?76 :((fi==1)?38 :19);
    const int   start = (fi==0)?0  :((fi==1)?17328:21660);
    float sx = cx/scale, sy = cy/scale;
    float fx = sx - floorf(sx); if (fx == 0.f) fx = 1.f;
    float fy = sy - floorf(sy); if (fy == 0.f) fy = 1.f;
    const int tlx = (int)(sx - fx);
    const int tly = (int)(sy - fy);
    return start + (tlx*hh + tly)*3 + bidx;
}

// full decode (with logf) — for the target-loss path
__device__ __forceinline__ void target_decode(float cx, float cy, float tw, float th,
                                              int& pidx, float& fx, float& fy,
                                              float& gtw, float& gth){
    const int best = best_anchor(tw,th);
    const int fi = best/3, bidx = best%3;
    const float scale = (fi==0)?8.f:((fi==1)?16.f:32.f);
    const int   hh    = (fi==0)?76 :((fi==1)?38 :19);
    const int   start = (fi==0)?0  :((fi==1)?17328:21660);
    const float aw = c_anch[best][0], ah = c_anch[best][1];
    float sx = cx/scale, sy = cy/scale;
    fx = sx - floorf(sx); if (fx == 0.f) fx = 1.f;
    fy = sy - floorf(sy); if (fy == 0.f) fy = 1.f;
    const int tlx = (int)(sx - fx);
    const int tly = (int)(sy - fy);
    gtw = logf(tw/aw); gth = logf(th/ah);
    pidx = start + (tlx*hh + tly)*3 + bidx;
}

// IoU-threshold test + softplus for one prediction row; div-free:
// max_t iou < 0.5  <=>  forall t: 3*inter_t < a1 + a2_t
__device__ __forceinline__ bool row_test(int j, nfloat4 r4, float p4,
                                         const float4* srect, const float* sa2,
                                         float& sp){
    float scale; int cx, cy, aidx;
    row_geom(j, scale, cx, cy, aidx);
    const float aw = c_anch[aidx][0], ah = c_anch[aidx][1];
    const float pcx = ((float)cx + sigm(r4.x))*scale;
    const float pcy = ((float)cy + sigm(r4.y))*scale;
    const float pw = aw*expf(r4.z);
    const float ph = ah*expf(r4.w);
    const float a1 = pw*ph;
    const float pxl = pcx - pw*0.5f, pyl = pcy - ph*0.5f;
    const float pxr = pcx + pw*0.5f, pyr = pcy + ph*0.5f;
    float md = -1.f;
    #pragma unroll
    for (int t = 0; t < NT; ++t){
        float4 T = srect[t];   // lx, ly, rx, ry
        float iw = fmaxf(fminf(pxr, T.z) - fmaxf(pxl, T.x), 0.f);
        float ih = fmaxf(fminf(pyr, T.w) - fmaxf(pyl, T.y), 0.f);
        float inter = iw*ih;
        md = fmaxf(md, fmaf(3.f, inter, -(a1 + sa2[t])));
    }
    // -max(log1p(-sigmoid(x)),-100) == min(softplus(x),100)
    sp = fminf(log1pf(expf(p4)), 100.f);
    return md < 0.f;
}

// ---------------- Main kernel ----------------
__global__ __launch_bounds__(256) void yolo_main(
        const float* __restrict__ f0, const float* __restrict__ f1,
        const float* __restrict__ f2,
        const float* __restrict__ tb, const int* __restrict__ tlab,
        const float* __restrict__ tsc,
        float* __restrict__ part_s, int* __restrict__ part_c,
        float* __restrict__ pbox, float* __restrict__ pobj,
        float* __restrict__ pcls,
        float* __restrict__ corr_s, int* __restrict__ corr_c){
    const int b   = blockIdx.y;
    const int x   = blockIdx.x;
    const int tid = threadIdx.x;

    __shared__ float4 sbox[NT];    // raw cxywh
    __shared__ float4 srect[NT];   // lx, ly, rx, ry
    __shared__ float  sa2[NT];     // target areas
    if (tid < NT){
        float4 T = ((const float4*)tb)[b*NT + tid];
        sbox[tid]  = T;
        srect[tid] = make_float4(T.x - T.z*0.5f, T.y - T.w*0.5f,
                                 T.x + T.z*0.5f, T.y + T.w*0.5f);
        sa2[tid] = T.z * T.w;
    }
    __syncthreads();

    if (x < RBLK){
        // ---- noobj path: 2 rows/thread, nontemporal (L1-bypass) loads ----
        const int j0 = x*512 + tid;
        const int j1 = j0 + 256;
        const bool a0 = (j0 < NPRED), a1 = (j1 < NPRED);
        const float* P0 = row_base(f0,f1,f2,b, a0 ? j0 : 0);
        const float* P1 = row_base(f0,f1,f2,b, a1 ? j1 : 0);
        // issue all 4 loads before any compute; bypass L1 (streaming, zero reuse)
        const nfloat4 r40 = __builtin_nontemporal_load(reinterpret_cast<const nfloat4*>(P0));
        const nfloat4 r41 = __builtin_nontemporal_load(reinterpret_cast<const nfloat4*>(P1));
        const float   p40 = __builtin_nontemporal_load(P0 + 4);
        const float   p41 = __builtin_nontemporal_load(P1 + 4);

        float nb = 0.f; int cnt = 0;
        if (a0){
            float sp;
            if (row_test(j0, r40, p40, srect, sa2, sp)){ nb += sp; cnt += 1; }
        }
        if (a1){
            float sp;
            if (row_test(j1, r41, p41, srect, sa2, sp)){ nb += sp; cnt += 1; }
        }
        #pragma unroll
        for (int off = 32; off > 0; off >>= 1){
            nb  += __shfl_down(nb, off);
            cnt += __shfl_down(cnt, off);
        }
        __shared__ float ws_s[4];
        __shared__ int   ws_c[4];
        const int wid = tid >> 6;
        if ((tid & 63) == 0){ ws_s[wid] = nb; ws_c[wid] = cnt; }
        __syncthreads();
        if (tid == 0){
            part_s[b*RBLK + x] = ws_s[0]+ws_s[1]+ws_s[2]+ws_s[3];
            part_c[b*RBLK + x] = ws_c[0]+ws_c[1]+ws_c[2]+ws_c[3];
        }
    } else {
        // ---- target path: one wave per target ----
        const int w    = tid >> 6;
        const int lane = tid & 63;
        const int t    = (x - RBLK)*4 + w;       // 0..19

        // per-lane positive index for dedup (lanes >= NT clamp to 19)
        const int bl = (lane < NT) ? lane : (NT-1);
        float4 BL = sbox[bl];
        int pidx_l = pos_index(BL.x, BL.y, BL.z, BL.w);
        // this wave's target
        float4 box = sbox[t];
        int pidx; float fx, fy, gtw, gth;
        target_decode(box.x, box.y, box.z, box.w, pidx, fx, fy, gtw, gth);
        unsigned long long mask = __ballot(pidx_l == pidx);
        const bool dup = (mask & ((1ull << t) - 1ull)) != 0ull;

        const float* p = row_base(f0,f1,f2,b,pidx);
        // broadcast row head (same address across lanes)
        const nfloat4 r4 = *reinterpret_cast<const nfloat4*>(p);
        const float   p4 = p[4];
        // correction test — bit-identical predicate to the noobj path
        float sp;
        bool qual = row_test(pidx, r4, p4, srect, sa2, sp);

        // class BCE spread across lanes
        const int lab = tlab[b*NT + t];
        float s;
        {
            float pc = sigm(p[5+lane]);
            float lg  = fmaxf(logf(pc),    -100.f);
            float lg1 = fmaxf(log1pf(-pc), -100.f);
            float tt = (lane == lab) ? 1.f : 0.f;
            s = -(tt*lg + (1.f-tt)*lg1);
        }
        if (lane < 16){
            int c = 64 + lane;
            float pc = sigm(p[5+c]);
            float lg  = fmaxf(logf(pc),    -100.f);
            float lg1 = fmaxf(log1pf(-pc), -100.f);
            float tt = (c == lab) ? 1.f : 0.f;
            s += -(tt*lg + (1.f-tt)*lg1);
        }
        #pragma unroll
        for (int off = 32; off > 0; off >>= 1) s += __shfl_down(s, off);

        if (lane == 0){
            const float w2 = 2.f - gtw*gth;
            float d0 = sigm(r4.x) - fx;
            float d1 = sigm(r4.y) - fy;
            float d2 = r4.z - gtw;
            float d3 = r4.w - gth;
            pbox[b*NT + t] = w2*(d0*d0 + d1*d1 + d2*d2 + d3*d3);
            float po = sigm(p4);
            float ts = tsc[b*NT + t];
            float lg  = fmaxf(logf(po),    -100.f);
            float lg1 = fmaxf(log1pf(-po), -100.f);
            pobj[b*NT + t] = -(ts*lg + (1.f-ts)*lg1);
            pcls[b*NT + t] = s;
            const bool take = qual && !dup;
            corr_s[b*NT + t] = take ? sp : 0.f;
            corr_c[b*NT + t] = take ? 1 : 0;
        }
    }
}

// ---------------- Finalize ----------------
__global__ __launch_bounds__(256) void yolo_final(
        const float* __restrict__ part_s, const int* __restrict__ part_c,
        const float* __restrict__ pbox, const float* __restrict__ pobj,
        const float* __restrict__ pcls,
        const float* __restrict__ corr_s, const int* __restrict__ corr_c,
        float* __restrict__ out){
    const int tid  = threadIdx.x;
    const int w    = tid >> 6;
    const int lane = tid & 63;
    __shared__ float rb[NB], ro[NB], rc[NB], rn[NB];
    for (int b = w; b < NB; b += 4){
        float s = 0.f; int c = 0;
        if (lane < RBLK){ s = part_s[b*RBLK + lane]; c = part_c[b*RBLK + lane]; }
        float A = 0.f, O = 0.f, C = 0.f, CS = 0.f; int CC = 0;
        if (lane < NT){
            A = pbox[b*NT + lane]; O = pobj[b*NT + lane]; C = pcls[b*NT + lane];
            CS = corr_s[b*NT + lane]; CC = corr_c[b*NT + lane];
        }
        #pragma unroll
        for (int off = 32; off > 0; off >>= 1){
            s  += __shfl_down(s, off);
            c  += __shfl_down(c, off);
            A  += __shfl_down(A, off);
            O  += __shfl_down(O, off);
            C  += __shfl_down(C, off);
            CS += __shfl_down(CS, off);
            CC += __shfl_down(CC, off);
        }
        if (lane == 0){
            float lb = A/(float)(NT*4);
            if (isinf(lb)) lb = 0.f;
            rb[b] = lb;
            ro[b] = O/(float)NT;
            rc[b] = C/(float)(NT*80);
            int   cnt = c - CC;
            float sum = s - CS;
            rn[b] = sum/(float)(cnt > 1 ? cnt : 1);
        }
    }
    __syncthreads();
    if (tid == 0){
        float sb=0.f, so=0.f, sc=0.f, sn=0.f;
        for (int b = 0; b < NB; ++b){ sb += rb[b]; so += ro[b]; sc += rc[b]; sn += rn[b]; }
        out[0] = sb/(float)NB;          // L_COORD * lbox.mean()
        out[1] = sc/(float)NB;          // L_CLS   * lcls.mean()
        out[2] = so/(float)NB;          // L_OBJ   * lobj.mean()
        out[3] = 0.5f*sn/(float)NB;     // L_NOOBJ * lnoobj.mean()
    }
}

extern "C" void kernel_launch(void* const* d_in, const int* in_sizes, int n_in,
                              void* d_out, int out_size, void* d_ws, size_t ws_size,
                              hipStream_t stream) {
    const float* f0  = (const float*)d_in[0];
    const float* f1  = (const float*)d_in[1];
    const float* f2  = (const float*)d_in[2];
    const float* tb  = (const float*)d_in[3];
    const int*   tlab= (const int*)  d_in[4];
    const float* tsc = (const float*)d_in[5];
    float* out = (float*)d_out;

    // ws layout — every slot plain-stored every call; no init, no atomics
    char* ws = (char*)d_ws;
    float* part_s = (float*)ws;                  // 16*45 f = 2880 B
    int*   part_c = (int*)  (ws + 2880);         // 16*45 i = 2880 B
    float* pbox   = (float*)(ws + 5760);         // 320 f
    float* pobj   = (float*)(ws + 7040);         // 320 f
    float* pcls   = (float*)(ws + 8320);         // 320 f
    float* corr_s = (float*)(ws + 9600);         // 320 f
    int*   corr_c = (int*)  (ws + 10880);        // 320 i

    dim3 grid(XTOT, NB);
    yolo_main<<<grid, 256, 0, stream>>>(f0, f1, f2, tb, tlab, tsc,
                                        part_s, part_c, pbox, pobj, pcls,
                                        corr_s, corr_c);
    yolo_final<<<1, 256, 0, stream>>>(part_s, part_c, pbox, pobj, pcls,
                                      corr_s, corr_c, out);
}